// Round 19
// baseline (8243.974 us; speedup 1.0000x reference)
//
#include <hip/hip_runtime.h>
#include <cstddef>
#include <cstdint>

#define HID   512
#define G4    2048   // 4*HID
#define NB    32     // batch
#define SEQL  1024
#define INPD  512
#define NBLK  128    // persistent blocks: block j owns hidden units [4j, 4j+4)
#define TPB   512

typedef _Float16 half8 __attribute__((ext_vector_type(8)));
typedef float    f32x4 __attribute__((ext_vector_type(4)));

__device__ __forceinline__ float sigm(float x) {
    return 1.0f / (1.0f + __expf(-x));
}
__device__ __forceinline__ float tanh_fast(float x) {
    float e = __expf(-2.0f * fabsf(x));
    float t = (1.0f - e) / (1.0f + e);
    return copysignf(t, x);
}

// Permuted gate index (type-major within block): g' = j*16 + ty*4 + uu
// orig W row for g': ty*HID + j*4 + uu.
__device__ __forceinline__ int orig_gate(int gp) {
    int r = gp & 15;
    return (r >> 2) * HID + (gp >> 4) * 4 + (r & 3);
}

// ---- one-time: W_hh fp32 [2048][512] -> fp16, per-block unit-major layout:
//      wh[j][p][k], p = uu*4 + ty  (B-operand rows for the persist MFMA)
__global__ __launch_bounds__(256) void conv_whh(const float* __restrict__ whh,
                                                _Float16* __restrict__ wh) {
    int e = blockIdx.x * 256 + threadIdx.x;   // e < 2048*512
    int R = e >> 9, k = e & 511;
    int ty = R >> 9, rem = R & 511;
    int j = rem >> 2, uu = rem & 3;
    int p = uu * 4 + ty;
    wh[((size_t)j * 16 + p) * 512 + k] = (_Float16)whh[e];
}

// ---- one-time: W_ih fp32 -> fp16 rows in xbuf-column (type-major g') order
__global__ __launch_bounds__(256) void conv_wih(const float* __restrict__ wih,
                                                _Float16* __restrict__ wi) {
    int e = blockIdx.x * 256 + threadIdx.x;   // e < 2048*512
    int R = e >> 9, k = e & 511;              // orig row R = ty*512 + u
    int ty = R >> 9, u = R & 511;
    int j = u >> 2, uu = u & 3;
    int gp = j * 16 + ty * 4 + uu;            // type-major permuted index
    wi[(size_t)gp * 512 + k] = (_Float16)wih[e];
}

// ---- one-time: permuted bias (bih+bhh)
__global__ __launch_bounds__(256) void conv_bias(const float* __restrict__ bih,
                                                 const float* __restrict__ bhh,
                                                 float* __restrict__ bp) {
    int gp = blockIdx.x * 256 + threadIdx.x;  // gp < 2048
    int og = orig_gate(gp);
    bp[gp] = bih[og] + bhh[og];
}

// ---- one-time: x fp32 -> fp16 (8 elems/thread)
__global__ __launch_bounds__(256) void conv_xh(const float* __restrict__ x,
                                               _Float16* __restrict__ xh) {
    int i = blockIdx.x * 256 + threadIdx.x;   // i < 32*1024*512/8
    const float4* s = (const float4*)(x + (size_t)i * 8);
    float4 a = s[0], b = s[1];
    half8 v = {(_Float16)a.x, (_Float16)a.y, (_Float16)a.z, (_Float16)a.w,
               (_Float16)b.x, (_Float16)b.y, (_Float16)b.z, (_Float16)b.w};
    *(half8*)(xh + (size_t)i * 8) = v;
}

// ---- one-time: h0 fp32 -> tagged u32 words (tag=0) into hbuf parity 0
__global__ __launch_bounds__(256) void conv_h0(const float* __restrict__ h0,
                                               unsigned* __restrict__ hb) {
    int e = blockIdx.x * 256 + threadIdx.x;   // e < NB*HID
    _Float16 hh = (_Float16)h0[e];
    unsigned short u;
    __builtin_memcpy(&u, &hh, 2);
    hb[e] = (unsigned)u;                       // tag 0 in high 16 bits
}

// ---- xproj: fp16 MFMA GEMM, xbuf[m][g'] = x[row(m)]·wih[orig(g')] + bias[g']
__global__ __launch_bounds__(256) void xproj_mfma(const _Float16* __restrict__ xh,
                                                  const _Float16* __restrict__ wi,
                                                  const float* __restrict__ bp,
                                                  float* __restrict__ xbuf,
                                                  int chunk, int SC) {
    __shared__ __align__(16) _Float16 As[64 * 36];
    __shared__ __align__(16) _Float16 Bs[64 * 36];

    const int m0 = blockIdx.x * 64;
    const int n0 = blockIdx.y * 64;
    const int t  = threadIdx.x;
    const int w  = t >> 6, lane = t & 63;

    const int sr = t >> 2, sq = (t & 3) * 8;
    const int m  = m0 + sr;
    const int b  = m / SC, tl = m % SC;
    const _Float16* arow = xh + ((size_t)b * SEQL + (size_t)chunk * SC + tl) * INPD + sq;
    const _Float16* brow = wi + (size_t)(n0 + sr) * 512 + sq;

    const int arow_l = 16 * w + (lane & 15);
    const int kl     = (lane >> 4) * 8;

    float bias[4];
    #pragma unroll
    for (int nt = 0; nt < 4; ++nt)
        bias[nt] = bp[n0 + nt * 16 + (lane & 15)];

    f32x4 acc[4] = {};
    for (int kk = 0; kk < 16; ++kk) {
        *(half8*)&As[sr * 36 + sq] = *(const half8*)(arow + kk * 32);
        *(half8*)&Bs[sr * 36 + sq] = *(const half8*)(brow + kk * 32);
        __syncthreads();
        half8 av = *(const half8*)&As[arow_l * 36 + kl];
        #pragma unroll
        for (int nt = 0; nt < 4; ++nt) {
            half8 bv = *(const half8*)&Bs[(nt * 16 + (lane & 15)) * 36 + kl];
            acc[nt] = __builtin_amdgcn_mfma_f32_16x16x32_f16(av, bv, acc[nt], 0, 0, 0);
        }
        __syncthreads();
    }

    #pragma unroll
    for (int nt = 0; nt < 4; ++nt) {
        int n = n0 + nt * 16 + (lane & 15);
        #pragma unroll
        for (int reg = 0; reg < 4; ++reg) {
            int mg = m0 + 16 * w + (lane >> 4) * 4 + reg;
            xbuf[(size_t)mg * G4 + n] = acc[nt][reg] + bias[nt];
        }
    }
}

// Persistent recurrence — r18 compute core + SELF-VALIDATING tagged h exchange.
// hbuf: 2 parities x [NB][HID] u32 words, word = (tag<<16)|fp16(h).
// Step g consumes tag g from parity g&1; publishes tag g+1 to parity (g+1)&1.
// Stage issues all 16 tagged u64 loads and retries ONLY stale words ->
// the data load IS the sync. No flags, no drain, no poll: 3 barriers/step,
// one LLC round trip, blocks pipeline with natural +/-1-step skew.
__global__ __launch_bounds__(512, 1)
void lstm_persist(const _Float16* __restrict__ wh,   // [NBLK][16][512] fp16
                  const float* __restrict__ xbuf,    // [NB*SC][G4] permuted cols
                  const float* __restrict__ c0,
                  unsigned long long* __restrict__ hbuf, // tagged [2][NB][HID/2] u64
                  float* __restrict__ cstate,        // [NB][HID]
                  float* __restrict__ out,           // [NB][SEQL][HID]
                  int step_base, int SC) {
    __shared__ __align__(16) _Float16 h_lds[32 * 520];   // [b][k]
    __shared__ __align__(16) float    part[32 * 67];     // [(reg*8+w)][lane]
    __shared__ __align__(16) float    gl[32 * 20];       // [b][p]

    const int j  = blockIdx.x;
    const int t  = threadIdx.x;
    const int u0 = 4 * j;

    // ---- MFMA role
    const int w    = t >> 6, lane = t & 63;
    const int mt   = w & 1, kg = w >> 1;
    const int arow = 16 * mt + (lane & 15);   // batch row (A)
    const int p_b  = lane & 15;               // gate row p (B, unit-major)
    const int kl   = (lane >> 4) * 8;         // half sub-offset

    // ---- reduce role: thread t -> output (batch b_t, gate n_r)
    const int mt_r = t & 1;
    const int idx  = t >> 1;
    const int n_r  = idx & 15;
    const int m_r  = idx >> 4;                            // 0..15
    const int b_t  = 16 * mt_r + m_r;
    const int lsrc = (m_r >> 2) * 16 + n_r;               // source lane
    const int regr = m_r & 3;                             // source reg
    const int xcol = 16 * j + (n_r & 3) * 4 + (n_r >> 2); // p -> type-major col

    // ---- B fragment into registers, once (16 VGPRs)
    half8 wf[4];
    {
        const _Float16* wrow = wh + ((size_t)j * 16 + p_b) * 512 + kg * 128 + kl;
        #pragma unroll
        for (int q = 0; q < 4; ++q)
            wf[q] = *(const half8*)(wrow + q * 32);
    }

    // ---- cell state: thread t<64 owns batch b_c = t&31, units u0+2pp, +1
    float cA = 0.0f, cB = 0.0f;
    const int b_c = t & 31, pp = t >> 5;   // valid when t<64
    if (t < 64) {
        const float* cs = (step_base == 0 ? c0 : cstate) + b_c * HID + u0 + 2 * pp;
        float2 cv = *(const float2*)cs;
        cA = cv.x; cB = cv.y;
    }

    for (int s = 0; s < SC; ++s) {
        const int g = step_base + s;

        // prefetch this lane's xg (no cross-step dependency)
        float xg = xbuf[((size_t)b_t * SC + s) * G4 + xcol];

        // ---- stage h: 16 tagged u64, per-word retry (load IS the sync)
        const unsigned long long* hs8 = hbuf + (size_t)(g & 1) * 8192;
        const unsigned long long pat = ((unsigned long long)(unsigned short)g << 48)
                                     | ((unsigned long long)(unsigned short)g << 16);
        unsigned long long v0,v1,v2,v3,v4,v5,v6,v7,v8,v9,v10,v11,v12,v13,v14,v15;
        bool k0,k1,k2,k3,k4,k5,k6,k7,k8,k9,k10,k11,k12,k13,k14,k15;
        #define LOADQ(i) \
            v##i = __hip_atomic_load(hs8 + i * 512 + t, __ATOMIC_RELAXED, \
                                     __HIP_MEMORY_SCOPE_AGENT); \
            k##i = ((v##i & 0xFFFF0000FFFF0000ull) == pat)
        LOADQ(0); LOADQ(1); LOADQ(2); LOADQ(3);
        LOADQ(4); LOADQ(5); LOADQ(6); LOADQ(7);
        LOADQ(8); LOADQ(9); LOADQ(10); LOADQ(11);
        LOADQ(12); LOADQ(13); LOADQ(14); LOADQ(15);
        for (;;) {
            bool all = k0 & k1 & k2 & k3 & k4 & k5 & k6 & k7
                     & k8 & k9 & k10 & k11 & k12 & k13 & k14 & k15;
            if (all) break;
            __builtin_amdgcn_s_sleep(1);
            #define RETRYQ(i) if (!k##i) { LOADQ(i); }
            RETRYQ(0); RETRYQ(1); RETRYQ(2); RETRYQ(3);
            RETRYQ(4); RETRYQ(5); RETRYQ(6); RETRYQ(7);
            RETRYQ(8); RETRYQ(9); RETRYQ(10); RETRYQ(11);
            RETRYQ(12); RETRYQ(13); RETRYQ(14); RETRYQ(15);
            #undef RETRYQ
        }
        #undef LOADQ
        // payload -> LDS (u32 = 2 fp16; consecutive t -> consecutive banks)
        #define STOREQ(i) { \
            int j8 = i * 512 + t; \
            int bq = j8 >> 8, r8 = j8 & 255; \
            unsigned payload = (unsigned)(v##i & 0xFFFF) \
                             | (((unsigned)(v##i >> 32) & 0xFFFFu) << 16); \
            ((unsigned*)h_lds)[bq * 260 + r8] = payload; }
        STOREQ(0); STOREQ(1); STOREQ(2); STOREQ(3);
        STOREQ(4); STOREQ(5); STOREQ(6); STOREQ(7);
        STOREQ(8); STOREQ(9); STOREQ(10); STOREQ(11);
        STOREQ(12); STOREQ(13); STOREQ(14); STOREQ(15);
        #undef STOREQ
        __syncthreads();   // sync1: h_lds complete

        // ---- phase A: 4 MFMA per wave
        f32x4 acc = {0.f, 0.f, 0.f, 0.f};
        #pragma unroll
        for (int q = 0; q < 4; ++q) {
            const int k = (kg * 4 + q) * 32 + kl;
            half8 av = *(const half8*)&h_lds[arow * 520 + k];
            acc = __builtin_amdgcn_mfma_f32_16x16x32_f16(av, wf[q], acc, 0, 0, 0);
        }
        // stride-67 planes: 4 scalar stores (2-way banks)
        #pragma unroll
        for (int r = 0; r < 4; ++r)
            part[(r * 8 + w) * 67 + lane] = acc[r];
        __syncthreads();   // sync2: part complete

        // ---- reduce 4 k-group partials + xg -> gl[b][p]
        float sum = xg;
        #pragma unroll
        for (int kgg = 0; kgg < 4; ++kgg)
            sum += part[(regr * 8 + kgg * 2 + mt_r) * 67 + lsrc];
        gl[b_t * 20 + n_r] = sum;
        __syncthreads();   // sync3: gl complete

        // ---- phase B: cell update + tagged publish (no drain, no flag)
        if (t < 64) {
            float4 gA = *(const float4*)&gl[b_c * 20 + 8 * pp];
            float4 gB = *(const float4*)&gl[b_c * 20 + 8 * pp + 4];
            cA = fmaf(sigm(gA.y), cA, sigm(gA.x) * tanh_fast(gA.z));
            float hA = sigm(gA.w) * tanh_fast(cA);
            cB = fmaf(sigm(gB.y), cB, sigm(gB.x) * tanh_fast(gB.z));
            float hB = sigm(gB.w) * tanh_fast(cB);

            _Float16 ha16 = (_Float16)hA, hb16 = (_Float16)hB;
            unsigned short hau, hbu;
            __builtin_memcpy(&hau, &ha16, 2);
            __builtin_memcpy(&hbu, &hb16, 2);
            const unsigned tg1 = (unsigned)(unsigned short)(g + 1);
            unsigned long long pv = ((unsigned long long)((tg1 << 16) | hau))
                                  | ((unsigned long long)((tg1 << 16) | hbu) << 32);
            __hip_atomic_store(hbuf + (size_t)((g + 1) & 1) * 8192
                                    + b_c * 256 + 2 * j + pp,
                               pv, __ATOMIC_RELAXED, __HIP_MEMORY_SCOPE_AGENT);

            // out store (fp32): nothing downstream depends on it this step
            float2 ov; ov.x = hA; ov.y = hB;
            *(float2*)&out[((size_t)b_c * SEQL + g) * HID + u0 + 2 * pp] = ov;
        }
        // no barrier: next stage's h_lds writes are ordered by sync1(g+1);
        // gl(g) reads finish before gl(g+1) writes (sync2(g+1) > phaseB(g)).
    }

    if (t < 64) {
        float2 cv; cv.x = cA; cv.y = cB;
        *(float2*)&cstate[b_c * HID + u0 + 2 * pp] = cv;
    }
}

__global__ __launch_bounds__(256) void finalize(const unsigned* __restrict__ hfin,
                                                const float* __restrict__ cs,
                                                float* __restrict__ out) {
    int i = blockIdx.x * blockDim.x + threadIdx.x;
    size_t base = (size_t)NB * SEQL * HID;
    if (i < NB * HID) {
        unsigned short u = (unsigned short)(hfin[i] & 0xFFFF);
        _Float16 hh;
        __builtin_memcpy(&hh, &u, 2);
        out[base + i] = (float)hh;
        out[base + NB * HID + i] = cs[i];
    }
}

extern "C" void kernel_launch(void* const* d_in, const int* in_sizes, int n_in,
                              void* d_out, int out_size, void* d_ws, size_t ws_size,
                              hipStream_t stream) {
    const float* x   = (const float*)d_in[0];
    const float* h0  = (const float*)d_in[1];
    const float* c0  = (const float*)d_in[2];
    const float* wih = (const float*)d_in[3];
    const float* whh = (const float*)d_in[4];
    const float* bih = (const float*)d_in[5];
    const float* bhh = (const float*)d_in[6];
    float* out = (float*)d_out;

    char* ws = (char*)d_ws;
    size_t off = 0;
    unsigned long long* hbuf = (unsigned long long*)(ws + off); off += 131072;   // 128 KB tagged
    float*     cstate = (float*)(ws + off);      off += 65536;                   // 64 KB
    _Float16*  wh_h   = (_Float16*)(ws + off);   off += 2097152;                 // 2 MB
    _Float16*  wi_h   = (_Float16*)(ws + off);   off += 2097152;                 // 2 MB
    float*     biasp  = (float*)(ws + off);      off += 8192;                    // 8 KB
    _Float16*  xh     = (_Float16*)(ws + off);   off += (size_t)NB * SEQL * INPD * 2; // 32 MB
    float*     xbuf   = (float*)(ws + off);

    size_t fixed = off;
    int SC = SEQL;
    while (SC > 64 && fixed + (size_t)NB * SC * G4 * sizeof(float) > ws_size) SC >>= 1;

    conv_whh<<<(2048 * 512) / 256, 256, 0, stream>>>(whh, wh_h);
    conv_wih<<<(2048 * 512) / 256, 256, 0, stream>>>(wih, wi_h);
    conv_bias<<<2048 / 256, 256, 0, stream>>>(bih, bhh, biasp);
    conv_xh<<<(NB * SEQL * INPD / 8) / 256, 256, 0, stream>>>(x, xh);
    conv_h0<<<(NB * HID) / 256, 256, 0, stream>>>(h0, (unsigned*)hbuf);

    int nchunks = SEQL / SC;
    for (int ch = 0; ch < nchunks; ++ch) {
        dim3 grd(NB * SC / 64, G4 / 64);
        xproj_mfma<<<grd, 256, 0, stream>>>(xh, wi_h, biasp, xbuf, ch, SC);
        lstm_persist<<<NBLK, TPB, 0, stream>>>(wh_h, xbuf, c0, hbuf,
                                               cstate, out, ch * SC, SC);
    }

    // total steps = 1024 (even) -> final h (tag 1024) lives in parity 0
    finalize<<<(NB * HID + 255) / 256, 256, 0, stream>>>((const unsigned*)hbuf,
                                                         cstate, out);
}